// Round 16
// baseline (188.398 us; speedup 1.0000x reference)
//
#include <hip/hip_runtime.h>
#include <hip/hip_bf16.h>
#include <stdint.h>

typedef __bf16 bf16_t;
typedef __bf16 bf16x8 __attribute__((ext_vector_type(8)));
typedef __bf16 bf16x4 __attribute__((ext_vector_type(4)));
typedef __bf16 bf16x2 __attribute__((ext_vector_type(2)));
typedef float floatx4 __attribute__((ext_vector_type(4)));

#define QSCALE 0.180336879f  /* 0.125 * log2(e) : fold score scale + exp2 domain into Q */

#if __has_builtin(__builtin_amdgcn_cvt_pk_bf16_f32)
#define HAS_PK_BF16 1
#endif

__device__ static inline void gll16(const void* g, void* l) {
    __builtin_amdgcn_global_load_lds((const __attribute__((address_space(1))) void*)g,
                                     (__attribute__((address_space(3))) void*)l, 16, 0, 0);
}

__device__ static inline bf16x8 pack8(const float* p) {
    bf16x8 o;
#ifdef HAS_PK_BF16
#pragma unroll
    for (int j = 0; j < 4; j++) {
        bf16x2 t2 = __builtin_amdgcn_cvt_pk_bf16_f32(p[2 * j], p[2 * j + 1]);
        o[2 * j] = t2[0]; o[2 * j + 1] = t2[1];
    }
#else
#pragma unroll
    for (int j = 0; j < 8; j++) o[j] = (bf16_t)p[j];
#endif
    return o;
}

// ---------------------------------------------------------------- fp32 -> bf16 (fused: inp, Wqkv, Wo)
__global__ __launch_bounds__(256) void cvt_all(const float* __restrict__ inp,
                                               const float* __restrict__ wqkv,
                                               const float* __restrict__ wo,
                                               bf16_t* __restrict__ o_inp,
                                               bf16_t* __restrict__ o_wqkv,
                                               bf16_t* __restrict__ o_wo) {
    int blk = blockIdx.x;
    const float* src;
    bf16_t* dst;
    if (blk < 4096)      { src = inp;  dst = o_inp; }
    else if (blk < 7168) { src = wqkv; dst = o_wqkv; blk -= 4096; }
    else                 { src = wo;   dst = o_wo;   blk -= 7168; }
    int i = blk * 256 + threadIdx.x;
    float4 v = ((const float4*)src)[i];
    float p[4] = {v.x, v.y, v.z, v.w};
    bf16x4 o;
#ifdef HAS_PK_BF16
    bf16x2 t0 = __builtin_amdgcn_cvt_pk_bf16_f32(p[0], p[1]);
    bf16x2 t1 = __builtin_amdgcn_cvt_pk_bf16_f32(p[2], p[3]);
    o[0] = t0[0]; o[1] = t0[1]; o[2] = t1[0]; o[3] = t1[1];
#else
    o[0] = (bf16_t)p[0]; o[1] = (bf16_t)p[1]; o[2] = (bf16_t)p[2]; o[3] = (bf16_t)p[3];
#endif
    ((bf16x4*)dst)[i] = o;
}

// ---------------------------------------------------------------- QKV GEMM
// R11 state: single barrier/iter (vmcnt(4) pre-barrier, prefetch post-barrier),
// 3 LDS buffers, chunk-XOR swizzle, XCD-chunked block swizzle.
// vT columns are t-PERMUTED within each 32-group: p = (t&~31) | q*8 | h*4 | r.
__global__ __launch_bounds__(256, 3)
void gemm_qkv(const bf16_t* __restrict__ A, const bf16_t* __restrict__ Bw,
              const float* __restrict__ bias,
              bf16_t* __restrict__ qk, bf16_t* __restrict__ vT) {
    constexpr int K = 1024;
    __shared__ bf16_t lA[3][128 * 32];
    __shared__ bf16_t lB[3][128 * 32];
    const int tid  = threadIdx.x;
    const int lane = tid & 63, wave = tid >> 6;
    const int quad = lane >> 4, l16 = lane & 15;
    const int wy = wave >> 1, wx = wave & 1;

    // XCD-chunked swizzle: 768 wg -> 96/XCD contiguous (768 % 8 == 0, bijective).
    const int L  = blockIdx.y * 24 + blockIdx.x;
    const int nL = (L & 7) * 96 + (L >> 3);
    const int bm = (nL / 24) * 128, bn = (nL % 24) * 128;

    const int c0 = tid, c1 = tid + 256;
    // source chunk pre-swizzle: LDS slot s of row r holds global chunk s ^ ((r>>1)&3)
    const int k0 = ((c0 & 3) ^ ((c0 >> 3) & 3)) * 8;
    const int k1 = ((c1 & 3) ^ ((c1 >> 3) & 3)) * 8;
    const bf16_t* Ap0 = A + (size_t)(bm + (c0 >> 2)) * K + k0;
    const bf16_t* Ap1 = A + (size_t)(bm + (c1 >> 2)) * K + k1;
    const bf16_t* Bp0 = Bw + (size_t)(bn + (c0 >> 2)) * K + k0;
    const bf16_t* Bp1 = Bw + (size_t)(bn + (c1 >> 2)) * K + k1;
    const int d0 = (wave * 64) * 8;          // wave-uniform dest (elems); HW adds lane*16B
    const int d1 = (256 + wave * 64) * 8;

    // read-side swizzled chunk
    const int sq8 = (quad ^ ((l16 >> 1) & 3)) * 8;

    floatx4 acc[4][4] = {};

    // prologue: stage tiles 0 and 1 (8 gll in flight)
    gll16(Ap0, &lA[0][d0]); gll16(Ap1, &lA[0][d1]);
    gll16(Bp0, &lB[0][d0]); gll16(Bp1, &lB[0][d1]);
    gll16(Ap0 + 32, &lA[1][d0]); gll16(Ap1 + 32, &lA[1][d1]);
    gll16(Bp0 + 32, &lB[1][d0]); gll16(Bp1 + 32, &lB[1][d1]);

    int cur = 0;
    for (int it = 0; it < 32; ++it) {
        if (it < 31) {
            asm volatile("s_waitcnt vmcnt(4)" ::: "memory");   // own tile-it glls landed
        } else {
            asm volatile("s_waitcnt vmcnt(0)" ::: "memory");
        }
        __builtin_amdgcn_s_barrier();          // everyone's tile-it writes published
        if (it < 30) {
            const int kt = (it + 2) * 32;
            const int nb = cur >= 1 ? cur - 1 : 2;        // (cur+2)%3 — read last at it-1
            gll16(Ap0 + kt, &lA[nb][d0]); gll16(Ap1 + kt, &lA[nb][d1]);
            gll16(Bp0 + kt, &lB[nb][d0]); gll16(Bp1 + kt, &lB[nb][d1]);
        }
        __builtin_amdgcn_sched_barrier(0);

        bf16x8 af[4], bfr[4];
#pragma unroll
        for (int i = 0; i < 4; i++) {
            af[i]  = *(const bf16x8*)(&lA[cur][(wy * 64 + i * 16 + l16) * 32 + sq8]);
            bfr[i] = *(const bf16x8*)(&lB[cur][(wx * 64 + i * 16 + l16) * 32 + sq8]);
        }
#pragma unroll
        for (int i = 0; i < 4; i++)
#pragma unroll
            for (int j = 0; j < 4; j++)
                acc[i][j] = __builtin_amdgcn_mfma_f32_16x16x32_bf16(af[i], bfr[j], acc[i][j], 0, 0, 0);

        cur = cur < 2 ? cur + 1 : 0;
    }

    const bool is_v = (bn >= 2048);
#pragma unroll
    for (int j = 0; j < 4; j++) {
        const int n = bn + wx * 64 + j * 16 + l16;
        const float bv = bias[n];
        const bool isq = (n < 1024);
#pragma unroll
        for (int i = 0; i < 4; i++) {
            const int mbase = bm + wy * 64 + i * 16 + quad * 4;
            if (!is_v) {
#pragma unroll
                for (int r = 0; r < 4; r++) {
                    float c = acc[i][j][r] + bv;
                    if (isq) c *= QSCALE;
                    qk[(size_t)(mbase + r) * 2048 + n] = (bf16_t)c;
                }
            } else {
                const int nn = n - 2048;             // h*64 + d
                const int b  = mbase >> 11;
                const int t  = mbase & 2047;         // 4-aligned
                const int vrow = b * 1024 + nn;      // (b*16+h)*64 + d
                const int pcol = (t & ~31) | (((t >> 2) & 3) << 3) | (((t >> 4) & 1) << 2);
                bf16x4 pack;
#pragma unroll
                for (int r = 0; r < 4; r++) pack[r] = (bf16_t)(acc[i][j][r] + bv);
                *(bf16x4*)(vT + (size_t)vrow * 2048 + pcol) = pack;
            }
        }
    }
}

// ---------------------------------------------------------------- flash attention (S^T, FULL-T, pipelined, 8-wave)
// R15 = R12 config (best measured e2e 181.87) + merged softmax/PV burst:
// per iter, load ALL 8 V frags, compute ALL 16 exp2 + both pack8, then one
// 10-MFMA PV burst — longer per-pipe bursts overlap better across the 4
// waves/SIMD, pack latency hides under the first PV MFMAs. +16 VGPR (vf[2][4])
// on a 40-VGPR baseline; occupancy grid-capped at 2 blocks/CU, unaffected.
__global__ __launch_bounds__(512, 4)
void attn_kernel(const bf16_t* __restrict__ qk, const bf16_t* __restrict__ vT,
                 bf16_t* __restrict__ Ofin) {
    __shared__ bf16_t Kbuf[3][64 * 64];   // [buf][ d-half(2) ][ t(64) ][ d(32) ]  (lane-linear)
    __shared__ bf16_t Vbuf[3][64 * 64];   // [buf][ t-half(2) ][ d(64) ][ p(32) ]
    const int tid  = threadIdx.x;
    const int lane = tid & 63, wave = tid >> 6;
    const int quad = lane >> 4, l16 = lane & 15;
    const int bid = blockIdx.x;
    const int s    = bid & 31;
    const int hl   = ((s & 7) << 2) | ((s >> 3) & 3);  // XCD-swizzle: 4 heads/XCD
    const int qt   = bid >> 5;
    const int b = hl >> 4, h = hl & 15;

    const bf16_t* Qbase = qk + (size_t)(b * 2048 + qt * 128 + wave * 16) * 2048 + h * 64;
    const bf16_t* Kbase = qk + (size_t)(b * 2048) * 2048 + 1024 + h * 64;
    const bf16_t* Vbase = vT + (size_t)(hl * 64) * 2048;

    // staging (512 threads): LDS elem offset tid*8 -> dhalf=tid>>8, row=(tid>>2)&63, chunk=tid&3
    const int srow  = (tid >> 2) & 63;
    const int dhalf = tid >> 8;
    const int sc8 = ((tid & 3) ^ ((tid >> 3) & 3)) * 8;   // source chunk pre-swizzle
    const bf16_t* Kg = Kbase + (size_t)srow * 2048 + dhalf * 32 + sc8;
    const bf16_t* Vg = Vbase + (size_t)srow * 2048 + dhalf * 32 + sc8;  // srow=d-row, dhalf=t-half
    const int wbase = wave * 512;   // wave-uniform LDS dest; HW adds lane*16B

    // read-side swizzled chunk: fragment rows are nt*16+l16 / ct*16+l16 -> bits 1-2 from l16 only
    const int xq8 = (quad ^ ((l16 >> 1) & 3)) * 8;

    floatx4 accO[4] = {};    // O[q=quad*4+r][d=ct*16+l16]
    floatx4 accL = {};       // l[q=quad*4+r] (ones-MFMA row sums)
    bf16x8 onesf;
#pragma unroll
    for (int j = 0; j < 8; j++) onesf[j] = (bf16_t)1.0f;

    // Q fragments FIRST (so iter-0's vmcnt(2) drains them with tile 0)
    bf16x8 qf[2];  // B-operand: n = q = l16, k = kc*32 + quad*8
#pragma unroll
    for (int kc = 0; kc < 2; kc++)
        qf[kc] = *(const bf16x8*)(Qbase + (size_t)l16 * 2048 + kc * 32 + quad * 8);

    // prologue: stage tiles 0 and 1 (2 gll/wave each)
    gll16(Kg, &Kbuf[0][wbase]);
    gll16(Vg, &Vbuf[0][wbase]);
    gll16(Kg + (size_t)64 * 2048, &Kbuf[1][wbase]);
    gll16(Vg + 64, &Vbuf[1][wbase]);

    int cur = 0;
    for (int it = 0; it < 32; ++it) {
        if (it < 31) {
            asm volatile("s_waitcnt vmcnt(2)" ::: "memory");   // own tile-it glls landed; it+1 in flight
        } else {
            asm volatile("s_waitcnt vmcnt(0)" ::: "memory");
        }
        __builtin_amdgcn_s_barrier();          // everyone's tile-it writes published
        if (it < 30) {
            const int nb = cur >= 1 ? cur - 1 : 2;        // (cur+2)%3 — read last at it-1
            gll16(Kg + (size_t)(it + 2) * 64 * 2048, &Kbuf[nb][wbase]);
            gll16(Vg + (it + 2) * 64, &Vbuf[nb][wbase]);
        }
        __builtin_amdgcn_sched_barrier(0);

        // S^T = K.Q^T : rows t (quad*4+r per nt-tile), cols q (l16)
        floatx4 st[4] = {};
        __builtin_amdgcn_s_setprio(1);
#pragma unroll
        for (int nt = 0; nt < 4; nt++) {
            bf16x8 k0 = *(const bf16x8*)&Kbuf[cur][(nt * 16 + l16) * 32 + xq8];
            bf16x8 k1 = *(const bf16x8*)&Kbuf[cur][2048 + (nt * 16 + l16) * 32 + xq8];
            st[nt] = __builtin_amdgcn_mfma_f32_16x16x32_bf16(k0, qf[0], st[nt], 0, 0, 0);
            st[nt] = __builtin_amdgcn_mfma_f32_16x16x32_bf16(k1, qf[1], st[nt], 0, 0, 0);
        }
        __builtin_amdgcn_s_setprio(0);

        // merged softmax: all V frags + all 16 exp2 + both packs, then one PV burst
        bf16x8 vf[2][4];
#pragma unroll
        for (int kc2 = 0; kc2 < 2; kc2++)
#pragma unroll
            for (int ct = 0; ct < 4; ct++)
                vf[kc2][ct] = *(const bf16x8*)&Vbuf[cur][kc2 * 2048 + (ct * 16 + l16) * 32 + xq8];
        bf16x8 pf[2];
#pragma unroll
        for (int kc2 = 0; kc2 < 2; kc2++) {
            float p[8];
#pragma unroll
            for (int j = 0; j < 8; j++)
                p[j] = __builtin_amdgcn_exp2f(st[kc2 * 2 + (j >> 2)][j & 3]);
            pf[kc2] = pack8(p);
        }
        __builtin_amdgcn_s_setprio(1);
#pragma unroll
        for (int kc2 = 0; kc2 < 2; kc2++) {
#pragma unroll
            for (int ct = 0; ct < 4; ct++)
                accO[ct] = __builtin_amdgcn_mfma_f32_16x16x32_bf16(pf[kc2], vf[kc2][ct], accO[ct], 0, 0, 0);
            accL = __builtin_amdgcn_mfma_f32_16x16x32_bf16(pf[kc2], onesf, accL, 0, 0, 0);
        }
        __builtin_amdgcn_s_setprio(0);

        cur = cur < 2 ? cur + 1 : 0;
    }

    // denominator already in accO layout: accL[r] = l for q=quad*4+r
    float linv[4];
#pragma unroll
    for (int r = 0; r < 4; r++) linv[r] = 1.0f / accL[r];

    // final O with "faithful bug" permutation: dest row (hl&1)*2048 + t, col (hl>>1)*64 + d
    const int b2 = hl & 1;
    const int colb = hl >> 1;
    const int rowb = b2 * 2048 + qt * 128 + wave * 16;
    bf16_t* outb = Ofin + (size_t)rowb * 1024 + colb * 64;
#pragma unroll
    for (int ct = 0; ct < 4; ct++)
#pragma unroll
        for (int r = 0; r < 4; r++)
            outb[(size_t)(quad * 4 + r) * 1024 + ct * 16 + l16] =
                (bf16_t)(accO[ct][r] * linv[r]);
}

// ---------------------------------------------------------------- O GEMM (plain, A already normalized)
// R11 state: single barrier/iter (vmcnt(3) pre-barrier, prefetch post-barrier),
// 3-buffer depth-2 pipeline, XCD-chunked swizzle.
__global__ __launch_bounds__(256, 4)
void gemm_o(const bf16_t* __restrict__ Op, const bf16_t* __restrict__ Bw,
            bf16_t* __restrict__ out) {
    constexpr int K = 1024;
    __shared__ bf16_t lA[3][64 * 32];    // 3 x 4 KB
    __shared__ bf16_t lB[3][128 * 32];   // 3 x 8 KB
    const int tid  = threadIdx.x;
    const int lane = tid & 63, wave = tid >> 6;
    const int quad = lane >> 4, l16 = lane & 15;
    const int wy = wave >> 1, wx = wave & 1;   // wave tile: 32m x 64n

    // XCD-chunked swizzle: 512 wg, bijective (512 % 8 == 0).
    const int L  = blockIdx.y * 8 + blockIdx.x;
    const int nL = (L & 7) * 64 + (L >> 3);
    const int bm = (nL >> 3) * 64, bn = (nL & 7) * 128;

    // A: 64 rows x 4 chunks, one gll16/thread; source chunk pre-swizzled
    const int akc = ((tid & 3) ^ ((tid >> 3) & 3)) * 8;
    const bf16_t* Ap = Op + (size_t)(bm + (tid >> 2)) * K + akc;
    const int dA = wave * 512;
    const int cb0 = tid, cb1 = tid + 256;       // B: 128 rows x 4 chunks
    const int bk0 = ((cb0 & 3) ^ ((cb0 >> 3) & 3)) * 8;
    const int bk1 = ((cb1 & 3) ^ ((cb1 >> 3) & 3)) * 8;
    const bf16_t* Bp0 = Bw + (size_t)(bn + (cb0 >> 2)) * K + bk0;
    const bf16_t* Bp1 = Bw + (size_t)(bn + (cb1 >> 2)) * K + bk1;
    const int d0 = wave * 512;
    const int d1 = 2048 + wave * 512;

    // read-side swizzled chunk (fragment rows: bits 1-2 from l16 only)
    const int xq8 = (quad ^ ((l16 >> 1) & 3)) * 8;

    // prologue: stage tiles 0 and 1 (6 gll in flight)
    gll16(Ap, &lA[0][dA]);
    gll16(Bp0, &lB[0][d0]); gll16(Bp1, &lB[0][d1]);
    gll16(Ap + 32, &lA[1][dA]);
    gll16(Bp0 + 32, &lB[1][d0]); gll16(Bp1 + 32, &lB[1][d1]);

    floatx4 acc[2][4] = {};
    int cur = 0;
    for (int it = 0; it < 32; ++it) {
        if (it < 31) {
            asm volatile("s_waitcnt vmcnt(3)" ::: "memory");   // own tile-it glls landed
        } else {
            asm volatile("s_waitcnt vmcnt(0)" ::: "memory");
        }
        __builtin_amdgcn_s_barrier();
        if (it < 30) {
            const int kt = (it + 2) * 32;
            const int nb = cur >= 1 ? cur - 1 : 2;        // (cur+2)%3 — read last at it-1
            gll16(Ap + kt, &lA[nb][dA]);
            gll16(Bp0 + kt, &lB[nb][d0]); gll16(Bp1 + kt, &lB[nb][d1]);
        }
        __builtin_amdgcn_sched_barrier(0);

        bf16x8 af[2], bfr[4];
#pragma unroll
        for (int i = 0; i < 2; i++)
            af[i] = *(const bf16x8*)(&lA[cur][(wy * 32 + i * 16 + l16) * 32 + xq8]);
#pragma unroll
        for (int j = 0; j < 4; j++)
            bfr[j] = *(const bf16x8*)(&lB[cur][(wx * 64 + j * 16 + l16) * 32 + xq8]);
#pragma unroll
        for (int i = 0; i < 2; i++)
#pragma unroll
            for (int j = 0; j < 4; j++)
                acc[i][j] = __builtin_amdgcn_mfma_f32_16x16x32_bf16(af[i], bfr[j], acc[i][j], 0, 0, 0);

        cur = cur < 2 ? cur + 1 : 0;
    }
#pragma unroll
    for (int j = 0; j < 4; j++) {
        const int n = bn + wx * 64 + j * 16 + l16;
#pragma unroll
        for (int i = 0; i < 2; i++) {
            const int mbase = bm + wy * 32 + i * 16 + quad * 4;
#pragma unroll
            for (int r = 0; r < 4; r++)
                out[(size_t)(mbase + r) * 1024 + n] = (bf16_t)acc[i][j][r];
        }
    }
}

// ---------------------------------------------------------------- residual + LayerNorm (ao in bf16)
__global__ __launch_bounds__(256)
void ln_kernel(const float* __restrict__ inp, const bf16_t* __restrict__ ao,
               const float* __restrict__ gamma, const float* __restrict__ beta,
               float* __restrict__ out) {
    const int row = blockIdx.x, tid = threadIdx.x;
    const int wave = tid >> 6, lane = tid & 63;
    float4 a = ((const float4*)(inp + (size_t)row * 1024))[tid];
    bf16x4 c4 = ((const bf16x4*)(ao + (size_t)row * 1024))[tid];
    float x0 = a.x + (float)c4[0], x1 = a.y + (float)c4[1];
    float x2 = a.z + (float)c4[2], x3 = a.w + (float)c4[3];
    float s = x0 + x1 + x2 + x3;
    float sq = x0 * x0 + x1 * x1 + x2 * x2 + x3 * x3;
#pragma unroll
    for (int mm = 32; mm >= 1; mm >>= 1) {
        s += __shfl_xor(s, mm);
        sq += __shfl_xor(sq, mm);
    }
    __shared__ float rs[4], rq[4];
    if (lane == 0) { rs[wave] = s; rq[wave] = sq; }
    __syncthreads();
    s = rs[0] + rs[1] + rs[2] + rs[3];
    sq = rq[0] + rq[1] + rq[2] + rq[3];
    const float mu = s * (1.0f / 1024.0f);
    const float var = sq * (1.0f / 1024.0f) - mu * mu;
    const float rstd = rsqrtf(var + 1e-5f);
    float4 g = ((const float4*)gamma)[tid], bt = ((const float4*)beta)[tid];
    float4 o;
    o.x = (x0 - mu) * rstd * g.x + bt.x;
    o.y = (x1 - mu) * rstd * g.y + bt.y;
    o.z = (x2 - mu) * rstd * g.z + bt.z;
    o.w = (x3 - mu) * rstd * g.w + bt.w;
    ((float4*)(out + (size_t)row * 1024))[tid] = o;
}

// ---------------------------------------------------------------- launch
extern "C" void kernel_launch(void* const* d_in, const int* in_sizes, int n_in,
                              void* d_out, int out_size, void* d_ws, size_t ws_size,
                              hipStream_t stream) {
    const float* inp   = (const float*)d_in[0];
    const float* Wqkv  = (const float*)d_in[1];
    const float* bqkv  = (const float*)d_in[2];
    const float* Wo    = (const float*)d_in[3];
    const float* gamma = (const float*)d_in[4];
    const float* beta  = (const float*)d_in[5];
    float* out = (float*)d_out;

    // workspace layout (64 MB):
    //  0- 8 : inp_bf   (dead after gemm_qkv)
    //  8-14 : wqkv_bf  (dead after gemm_qkv)
    // 14-16 : wo_bf    (live until gemm_o)
    // 16-32 : qk_buf   (dead after attn)
    // 32-40 : vT_buf   (dead after attn)      -> ao_bf overlay (8 MB, gemm_o out)
    // 48-56 : ofin     (8 MB, final normalized attn_vec, read by gemm_o)
    char* ws = (char*)d_ws;
    bf16_t* inp_bf  = (bf16_t*)(ws);
    bf16_t* wqkv_bf = (bf16_t*)(ws + (8u << 20));
    bf16_t* wo_bf   = (bf16_t*)(ws + (14u << 20));
    bf16_t* qk_buf  = (bf16_t*)(ws + (16u << 20));
    bf16_t* vT_buf  = (bf16_t*)(ws + (32u << 20));
    bf16_t* ao_bf   = (bf16_t*)(ws + (32u << 20));
    bf16_t* ofin    = (bf16_t*)(ws + (48u << 20));

    cvt_all<<<8192, 256, 0, stream>>>(inp, Wqkv, Wo, inp_bf, wqkv_bf, wo_bf);
    gemm_qkv<<<dim3(24, 32), 256, 0, stream>>>(inp_bf, wqkv_bf, bqkv, qk_buf, vT_buf);
    attn_kernel<<<512, 512, 0, stream>>>(qk_buf, vT_buf, ofin);
    gemm_o<<<dim3(8, 64), 256, 0, stream>>>(ofin, wo_bf, ao_bf);
    ln_kernel<<<4096, 256, 0, stream>>>(inp, ao_bf, gamma, beta, out);
}

// Round 17
// 182.774 us; speedup vs baseline: 1.0308x; 1.0308x over previous
//
#include <hip/hip_runtime.h>
#include <hip/hip_bf16.h>
#include <stdint.h>

typedef __bf16 bf16_t;
typedef __bf16 bf16x8 __attribute__((ext_vector_type(8)));
typedef __bf16 bf16x4 __attribute__((ext_vector_type(4)));
typedef __bf16 bf16x2 __attribute__((ext_vector_type(2)));
typedef float floatx4 __attribute__((ext_vector_type(4)));

#define QSCALE 0.180336879f  /* 0.125 * log2(e) : fold score scale + exp2 domain into Q */

#if __has_builtin(__builtin_amdgcn_cvt_pk_bf16_f32)
#define HAS_PK_BF16 1
#endif

__device__ static inline void gll16(const void* g, void* l) {
    __builtin_amdgcn_global_load_lds((const __attribute__((address_space(1))) void*)g,
                                     (__attribute__((address_space(3))) void*)l, 16, 0, 0);
}

__device__ static inline bf16x8 pack8(const float* p) {
    bf16x8 o;
#ifdef HAS_PK_BF16
#pragma unroll
    for (int j = 0; j < 4; j++) {
        bf16x2 t2 = __builtin_amdgcn_cvt_pk_bf16_f32(p[2 * j], p[2 * j + 1]);
        o[2 * j] = t2[0]; o[2 * j + 1] = t2[1];
    }
#else
#pragma unroll
    for (int j = 0; j < 8; j++) o[j] = (bf16_t)p[j];
#endif
    return o;
}

// ---------------------------------------------------------------- fp32 -> bf16 (fused: inp, Wqkv, Wo)
__global__ __launch_bounds__(256) void cvt_all(const float* __restrict__ inp,
                                               const float* __restrict__ wqkv,
                                               const float* __restrict__ wo,
                                               bf16_t* __restrict__ o_inp,
                                               bf16_t* __restrict__ o_wqkv,
                                               bf16_t* __restrict__ o_wo) {
    int blk = blockIdx.x;
    const float* src;
    bf16_t* dst;
    if (blk < 4096)      { src = inp;  dst = o_inp; }
    else if (blk < 7168) { src = wqkv; dst = o_wqkv; blk -= 4096; }
    else                 { src = wo;   dst = o_wo;   blk -= 7168; }
    int i = blk * 256 + threadIdx.x;
    float4 v = ((const float4*)src)[i];
    float p[4] = {v.x, v.y, v.z, v.w};
    bf16x4 o;
#ifdef HAS_PK_BF16
    bf16x2 t0 = __builtin_amdgcn_cvt_pk_bf16_f32(p[0], p[1]);
    bf16x2 t1 = __builtin_amdgcn_cvt_pk_bf16_f32(p[2], p[3]);
    o[0] = t0[0]; o[1] = t0[1]; o[2] = t1[0]; o[3] = t1[1];
#else
    o[0] = (bf16_t)p[0]; o[1] = (bf16_t)p[1]; o[2] = (bf16_t)p[2]; o[3] = (bf16_t)p[3];
#endif
    ((bf16x4*)dst)[i] = o;
}

// ---------------------------------------------------------------- QKV GEMM
// R11 state: single barrier/iter (vmcnt(4) pre-barrier, prefetch post-barrier),
// 3 LDS buffers, chunk-XOR swizzle, XCD-chunked block swizzle.
// vT columns are t-PERMUTED within each 32-group: p = (t&~31) | q*8 | h*4 | r.
__global__ __launch_bounds__(256, 3)
void gemm_qkv(const bf16_t* __restrict__ A, const bf16_t* __restrict__ Bw,
              const float* __restrict__ bias,
              bf16_t* __restrict__ qk, bf16_t* __restrict__ vT) {
    constexpr int K = 1024;
    __shared__ bf16_t lA[3][128 * 32];
    __shared__ bf16_t lB[3][128 * 32];
    const int tid  = threadIdx.x;
    const int lane = tid & 63, wave = tid >> 6;
    const int quad = lane >> 4, l16 = lane & 15;
    const int wy = wave >> 1, wx = wave & 1;

    // XCD-chunked swizzle: 768 wg -> 96/XCD contiguous (768 % 8 == 0, bijective).
    const int L  = blockIdx.y * 24 + blockIdx.x;
    const int nL = (L & 7) * 96 + (L >> 3);
    const int bm = (nL / 24) * 128, bn = (nL % 24) * 128;

    const int c0 = tid, c1 = tid + 256;
    // source chunk pre-swizzle: LDS slot s of row r holds global chunk s ^ ((r>>1)&3)
    const int k0 = ((c0 & 3) ^ ((c0 >> 3) & 3)) * 8;
    const int k1 = ((c1 & 3) ^ ((c1 >> 3) & 3)) * 8;
    const bf16_t* Ap0 = A + (size_t)(bm + (c0 >> 2)) * K + k0;
    const bf16_t* Ap1 = A + (size_t)(bm + (c1 >> 2)) * K + k1;
    const bf16_t* Bp0 = Bw + (size_t)(bn + (c0 >> 2)) * K + k0;
    const bf16_t* Bp1 = Bw + (size_t)(bn + (c1 >> 2)) * K + k1;
    const int d0 = (wave * 64) * 8;          // wave-uniform dest (elems); HW adds lane*16B
    const int d1 = (256 + wave * 64) * 8;

    // read-side swizzled chunk
    const int sq8 = (quad ^ ((l16 >> 1) & 3)) * 8;

    floatx4 acc[4][4] = {};

    // prologue: stage tiles 0 and 1 (8 gll in flight)
    gll16(Ap0, &lA[0][d0]); gll16(Ap1, &lA[0][d1]);
    gll16(Bp0, &lB[0][d0]); gll16(Bp1, &lB[0][d1]);
    gll16(Ap0 + 32, &lA[1][d0]); gll16(Ap1 + 32, &lA[1][d1]);
    gll16(Bp0 + 32, &lB[1][d0]); gll16(Bp1 + 32, &lB[1][d1]);

    int cur = 0;
    for (int it = 0; it < 32; ++it) {
        if (it < 31) {
            asm volatile("s_waitcnt vmcnt(4)" ::: "memory");   // own tile-it glls landed
        } else {
            asm volatile("s_waitcnt vmcnt(0)" ::: "memory");
        }
        __builtin_amdgcn_s_barrier();          // everyone's tile-it writes published
        if (it < 30) {
            const int kt = (it + 2) * 32;
            const int nb = cur >= 1 ? cur - 1 : 2;        // (cur+2)%3 — read last at it-1
            gll16(Ap0 + kt, &lA[nb][d0]); gll16(Ap1 + kt, &lA[nb][d1]);
            gll16(Bp0 + kt, &lB[nb][d0]); gll16(Bp1 + kt, &lB[nb][d1]);
        }
        __builtin_amdgcn_sched_barrier(0);

        bf16x8 af[4], bfr[4];
#pragma unroll
        for (int i = 0; i < 4; i++) {
            af[i]  = *(const bf16x8*)(&lA[cur][(wy * 64 + i * 16 + l16) * 32 + sq8]);
            bfr[i] = *(const bf16x8*)(&lB[cur][(wx * 64 + i * 16 + l16) * 32 + sq8]);
        }
#pragma unroll
        for (int i = 0; i < 4; i++)
#pragma unroll
            for (int j = 0; j < 4; j++)
                acc[i][j] = __builtin_amdgcn_mfma_f32_16x16x32_bf16(af[i], bfr[j], acc[i][j], 0, 0, 0);

        cur = cur < 2 ? cur + 1 : 0;
    }

    const bool is_v = (bn >= 2048);
#pragma unroll
    for (int j = 0; j < 4; j++) {
        const int n = bn + wx * 64 + j * 16 + l16;
        const float bv = bias[n];
        const bool isq = (n < 1024);
#pragma unroll
        for (int i = 0; i < 4; i++) {
            const int mbase = bm + wy * 64 + i * 16 + quad * 4;
            if (!is_v) {
#pragma unroll
                for (int r = 0; r < 4; r++) {
                    float c = acc[i][j][r] + bv;
                    if (isq) c *= QSCALE;
                    qk[(size_t)(mbase + r) * 2048 + n] = (bf16_t)c;
                }
            } else {
                const int nn = n - 2048;             // h*64 + d
                const int b  = mbase >> 11;
                const int t  = mbase & 2047;         // 4-aligned
                const int vrow = b * 1024 + nn;      // (b*16+h)*64 + d
                const int pcol = (t & ~31) | (((t >> 2) & 3) << 3) | (((t >> 4) & 1) << 2);
                bf16x4 pack;
#pragma unroll
                for (int r = 0; r < 4; r++) pack[r] = (bf16_t)(acc[i][j][r] + bv);
                *(bf16x4*)(vT + (size_t)vrow * 2048 + pcol) = pack;
            }
        }
    }
}

// ---------------------------------------------------------------- flash attention (S^T, FULL-T, T15 cross-iter pipeline)
// R16: QK(it) overlapped with softmax+PV(it-1). The two are independent ->
// compiler co-issues QK MFMAs (matrix pipe) with exp2/pack (VALU pipe) in one
// wave, breaking the serial QK->exp->PV chain that capped both pipes at ~35%.
// 4 K/V buffers (64 KB): PV(it-1) reads buf (it-1)&3 while prefetch writes
// (it+2)&3 — disjoint mod 4; barrier ordering as in R11. 8 waves x 16 q-rows,
// grid 512 (2 blocks/CU, grid-capped). ones-MFMA denominator; vmcnt(2) depth-2.
__global__ __launch_bounds__(512, 2)
void attn_kernel(const bf16_t* __restrict__ qk, const bf16_t* __restrict__ vT,
                 bf16_t* __restrict__ Ofin) {
    __shared__ bf16_t Kbuf[4][64 * 64];   // [buf][ d-half(2) ][ t(64) ][ d(32) ]
    __shared__ bf16_t Vbuf[4][64 * 64];   // [buf][ t-half(2) ][ d(64) ][ p(32) ]
    const int tid  = threadIdx.x;
    const int lane = tid & 63, wave = tid >> 6;
    const int quad = lane >> 4, l16 = lane & 15;
    const int bid = blockIdx.x;
    const int s    = bid & 31;
    const int hl   = ((s & 7) << 2) | ((s >> 3) & 3);  // XCD-swizzle: 4 heads/XCD
    const int qt   = bid >> 5;
    const int b = hl >> 4, h = hl & 15;

    const bf16_t* Qbase = qk + (size_t)(b * 2048 + qt * 128 + wave * 16) * 2048 + h * 64;
    const bf16_t* Kbase = qk + (size_t)(b * 2048) * 2048 + 1024 + h * 64;
    const bf16_t* Vbase = vT + (size_t)(hl * 64) * 2048;

    // staging (512 threads): LDS elem offset tid*8 -> dhalf=tid>>8, row=(tid>>2)&63, chunk=tid&3
    const int srow  = (tid >> 2) & 63;
    const int dhalf = tid >> 8;
    const int sc8 = ((tid & 3) ^ ((tid >> 3) & 3)) * 8;   // source chunk pre-swizzle
    const bf16_t* Kg = Kbase + (size_t)srow * 2048 + dhalf * 32 + sc8;
    const bf16_t* Vg = Vbase + (size_t)srow * 2048 + dhalf * 32 + sc8;  // srow=d-row, dhalf=t-half
    const int wbase = wave * 512;   // wave-uniform LDS dest; HW adds lane*16B

    // read-side swizzled chunk: fragment rows are nt*16+l16 / ct*16+l16 -> bits 1-2 from l16 only
    const int xq8 = (quad ^ ((l16 >> 1) & 3)) * 8;

    floatx4 accO[4] = {};    // O[q=quad*4+r][d=ct*16+l16]
    floatx4 accL = {};       // l[q=quad*4+r] (ones-MFMA row sums)
    bf16x8 onesf;
#pragma unroll
    for (int j = 0; j < 8; j++) onesf[j] = (bf16_t)1.0f;

    // Q fragments FIRST (so iter-0's vmcnt(2) drains them with tile 0)
    bf16x8 qf[2];  // B-operand: n = q = l16, k = kc*32 + quad*8
#pragma unroll
    for (int kc = 0; kc < 2; kc++)
        qf[kc] = *(const bf16x8*)(Qbase + (size_t)l16 * 2048 + kc * 32 + quad * 8);

    // prologue: stage tiles 0 and 1 (2 gll/wave each)
    gll16(Kg, &Kbuf[0][wbase]);
    gll16(Vg, &Vbuf[0][wbase]);
    gll16(Kg + (size_t)64 * 2048, &Kbuf[1][wbase]);
    gll16(Vg + 64, &Vbuf[1][wbase]);

    floatx4 st_prev[4];
    for (int it = 0; it < 32; ++it) {
        if (it < 31) {
            asm volatile("s_waitcnt vmcnt(2)" ::: "memory");   // own tile-it glls landed; it+1 in flight
        } else {
            asm volatile("s_waitcnt vmcnt(0)" ::: "memory");
        }
        __builtin_amdgcn_s_barrier();          // everyone's tile-it writes published
        if (it < 30) {
            const int nb = (it + 2) & 3;       // holds tile it-2, last read at iter it-1 (pre-barrier)
            gll16(Kg + (size_t)(it + 2) * 64 * 2048, &Kbuf[nb][wbase]);
            gll16(Vg + (it + 2) * 64, &Vbuf[nb][wbase]);
        }
        __builtin_amdgcn_sched_barrier(0);

        const int kb = it & 3;
        // QK for tile it (matrix pipe) — independent of softmax/PV of tile it-1 (VALU)
        floatx4 st[4] = {};
#pragma unroll
        for (int nt = 0; nt < 4; nt++) {
            bf16x8 k0 = *(const bf16x8*)&Kbuf[kb][(nt * 16 + l16) * 32 + xq8];
            bf16x8 k1 = *(const bf16x8*)&Kbuf[kb][2048 + (nt * 16 + l16) * 32 + xq8];
            st[nt] = __builtin_amdgcn_mfma_f32_16x16x32_bf16(k0, qf[0], st[nt], 0, 0, 0);
            st[nt] = __builtin_amdgcn_mfma_f32_16x16x32_bf16(k1, qf[1], st[nt], 0, 0, 0);
        }
        if (it > 0) {
            const int vb = (it - 1) & 3;
            bf16x8 vf[2][4];
#pragma unroll
            for (int kc2 = 0; kc2 < 2; kc2++)
#pragma unroll
                for (int ct = 0; ct < 4; ct++)
                    vf[kc2][ct] = *(const bf16x8*)&Vbuf[vb][kc2 * 2048 + (ct * 16 + l16) * 32 + xq8];
            bf16x8 pf[2];
#pragma unroll
            for (int kc2 = 0; kc2 < 2; kc2++) {
                float p[8];
#pragma unroll
                for (int j = 0; j < 8; j++)
                    p[j] = __builtin_amdgcn_exp2f(st_prev[kc2 * 2 + (j >> 2)][j & 3]);
                pf[kc2] = pack8(p);
            }
#pragma unroll
            for (int kc2 = 0; kc2 < 2; kc2++) {
#pragma unroll
                for (int ct = 0; ct < 4; ct++)
                    accO[ct] = __builtin_amdgcn_mfma_f32_16x16x32_bf16(pf[kc2], vf[kc2][ct], accO[ct], 0, 0, 0);
                accL = __builtin_amdgcn_mfma_f32_16x16x32_bf16(pf[kc2], onesf, accL, 0, 0, 0);
            }
        }
#pragma unroll
        for (int nt = 0; nt < 4; nt++) st_prev[nt] = st[nt];
    }
    // epilogue: softmax+PV for tile 31 (Vbuf[3], no writes since its prefetch)
    {
        const int vb = 31 & 3;
        bf16x8 vf[2][4];
#pragma unroll
        for (int kc2 = 0; kc2 < 2; kc2++)
#pragma unroll
            for (int ct = 0; ct < 4; ct++)
                vf[kc2][ct] = *(const bf16x8*)&Vbuf[vb][kc2 * 2048 + (ct * 16 + l16) * 32 + xq8];
        bf16x8 pf[2];
#pragma unroll
        for (int kc2 = 0; kc2 < 2; kc2++) {
            float p[8];
#pragma unroll
            for (int j = 0; j < 8; j++)
                p[j] = __builtin_amdgcn_exp2f(st_prev[kc2 * 2 + (j >> 2)][j & 3]);
            pf[kc2] = pack8(p);
        }
#pragma unroll
        for (int kc2 = 0; kc2 < 2; kc2++) {
#pragma unroll
            for (int ct = 0; ct < 4; ct++)
                accO[ct] = __builtin_amdgcn_mfma_f32_16x16x32_bf16(pf[kc2], vf[kc2][ct], accO[ct], 0, 0, 0);
            accL = __builtin_amdgcn_mfma_f32_16x16x32_bf16(pf[kc2], onesf, accL, 0, 0, 0);
        }
    }

    // denominator already in accO layout: accL[r] = l for q=quad*4+r
    float linv[4];
#pragma unroll
    for (int r = 0; r < 4; r++) linv[r] = 1.0f / accL[r];

    // final O with "faithful bug" permutation: dest row (hl&1)*2048 + t, col (hl>>1)*64 + d
    const int b2 = hl & 1;
    const int colb = hl >> 1;
    const int rowb = b2 * 2048 + qt * 128 + wave * 16;
    bf16_t* outb = Ofin + (size_t)rowb * 1024 + colb * 64;
#pragma unroll
    for (int ct = 0; ct < 4; ct++)
#pragma unroll
        for (int r = 0; r < 4; r++)
            outb[(size_t)(quad * 4 + r) * 1024 + ct * 16 + l16] =
                (bf16_t)(accO[ct][r] * linv[r]);
}

// ---------------------------------------------------------------- O GEMM (plain, A already normalized)
// R11 state: single barrier/iter (vmcnt(3) pre-barrier, prefetch post-barrier),
// 3-buffer depth-2 pipeline, XCD-chunked swizzle.
__global__ __launch_bounds__(256, 4)
void gemm_o(const bf16_t* __restrict__ Op, const bf16_t* __restrict__ Bw,
            bf16_t* __restrict__ out) {
    constexpr int K = 1024;
    __shared__ bf16_t lA[3][64 * 32];    // 3 x 4 KB
    __shared__ bf16_t lB[3][128 * 32];   // 3 x 8 KB
    const int tid  = threadIdx.x;
    const int lane = tid & 63, wave = tid >> 6;
    const int quad = lane >> 4, l16 = lane & 15;
    const int wy = wave >> 1, wx = wave & 1;   // wave tile: 32m x 64n

    // XCD-chunked swizzle: 512 wg, bijective (512 % 8 == 0).
    const int L  = blockIdx.y * 8 + blockIdx.x;
    const int nL = (L & 7) * 64 + (L >> 3);
    const int bm = (nL >> 3) * 64, bn = (nL & 7) * 128;

    // A: 64 rows x 4 chunks, one gll16/thread; source chunk pre-swizzled
    const int akc = ((tid & 3) ^ ((tid >> 3) & 3)) * 8;
    const bf16_t* Ap = Op + (size_t)(bm + (tid >> 2)) * K + akc;
    const int dA = wave * 512;
    const int cb0 = tid, cb1 = tid + 256;       // B: 128 rows x 4 chunks
    const int bk0 = ((cb0 & 3) ^ ((cb0 >> 3) & 3)) * 8;
    const int bk1 = ((cb1 & 3) ^ ((cb1 >> 3) & 3)) * 8;
    const bf16_t* Bp0 = Bw + (size_t)(bn + (cb0 >> 2)) * K + bk0;
    const bf16_t* Bp1 = Bw + (size_t)(bn + (cb1 >> 2)) * K + bk1;
    const int d0 = wave * 512;
    const int d1 = 2048 + wave * 512;

    // read-side swizzled chunk (fragment rows: bits 1-2 from l16 only)
    const int xq8 = (quad ^ ((l16 >> 1) & 3)) * 8;

    // prologue: stage tiles 0 and 1 (6 gll in flight)
    gll16(Ap, &lA[0][dA]);
    gll16(Bp0, &lB[0][d0]); gll16(Bp1, &lB[0][d1]);
    gll16(Ap + 32, &lA[1][dA]);
    gll16(Bp0 + 32, &lB[1][d0]); gll16(Bp1 + 32, &lB[1][d1]);

    floatx4 acc[2][4] = {};
    int cur = 0;
    for (int it = 0; it < 32; ++it) {
        if (it < 31) {
            asm volatile("s_waitcnt vmcnt(3)" ::: "memory");   // own tile-it glls landed
        } else {
            asm volatile("s_waitcnt vmcnt(0)" ::: "memory");
        }
        __builtin_amdgcn_s_barrier();
        if (it < 30) {
            const int kt = (it + 2) * 32;
            const int nb = cur >= 1 ? cur - 1 : 2;        // (cur+2)%3 — read last at it-1
            gll16(Ap + kt, &lA[nb][dA]);
            gll16(Bp0 + kt, &lB[nb][d0]); gll16(Bp1 + kt, &lB[nb][d1]);
        }
        __builtin_amdgcn_sched_barrier(0);

        bf16x8 af[2], bfr[4];
#pragma unroll
        for (int i = 0; i < 2; i++)
            af[i] = *(const bf16x8*)(&lA[cur][(wy * 32 + i * 16 + l16) * 32 + xq8]);
#pragma unroll
        for (int j = 0; j < 4; j++)
            bfr[j] = *(const bf16x8*)(&lB[cur][(wx * 64 + j * 16 + l16) * 32 + xq8]);
#pragma unroll
        for (int i = 0; i < 2; i++)
#pragma unroll
            for (int j = 0; j < 4; j++)
                acc[i][j] = __builtin_amdgcn_mfma_f32_16x16x32_bf16(af[i], bfr[j], acc[i][j], 0, 0, 0);

        cur = cur < 2 ? cur + 1 : 0;
    }
#pragma unroll
    for (int j = 0; j < 4; j++) {
        const int n = bn + wx * 64 + j * 16 + l16;
#pragma unroll
        for (int i = 0; i < 2; i++) {
            const int mbase = bm + wy * 32 + i * 16 + quad * 4;
#pragma unroll
            for (int r = 0; r < 4; r++)
                out[(size_t)(mbase + r) * 1024 + n] = (bf16_t)acc[i][j][r];
        }
    }
}

// ---------------------------------------------------------------- residual + LayerNorm (ao in bf16)
__global__ __launch_bounds__(256)
void ln_kernel(const float* __restrict__ inp, const bf16_t* __restrict__ ao,
               const float* __restrict__ gamma, const float* __restrict__ beta,
               float* __restrict__ out) {
    const int row = blockIdx.x, tid = threadIdx.x;
    const int wave = tid >> 6, lane = tid & 63;
    float4 a = ((const float4*)(inp + (size_t)row * 1024))[tid];
    bf16x4 c4 = ((const bf16x4*)(ao + (size_t)row * 1024))[tid];
    float x0 = a.x + (float)c4[0], x1 = a.y + (float)c4[1];
    float x2 = a.z + (float)c4[2], x3 = a.w + (float)c4[3];
    float s = x0 + x1 + x2 + x3;
    float sq = x0 * x0 + x1 * x1 + x2 * x2 + x3 * x3;
#pragma unroll
    for (int mm = 32; mm >= 1; mm >>= 1) {
        s += __shfl_xor(s, mm);
        sq += __shfl_xor(sq, mm);
    }
    __shared__ float rs[4], rq[4];
    if (lane == 0) { rs[wave] = s; rq[wave] = sq; }
    __syncthreads();
    s = rs[0] + rs[1] + rs[2] + rs[3];
    sq = rq[0] + rq[1] + rq[2] + rq[3];
    const float mu = s * (1.0f / 1024.0f);
    const float var = sq * (1.0f / 1024.0f) - mu * mu;
    const float rstd = rsqrtf(var + 1e-5f);
    float4 g = ((const float4*)gamma)[tid], bt = ((const float4*)beta)[tid];
    float4 o;
    o.x = (x0 - mu) * rstd * g.x + bt.x;
    o.y = (x1 - mu) * rstd * g.y + bt.y;
    o.z = (x2 - mu) * rstd * g.z + bt.z;
    o.w = (x3 - mu) * rstd * g.w + bt.w;
    ((float4*)(out + (size_t)row * 1024))[tid] = o;
}

// ---------------------------------------------------------------- launch
extern "C" void kernel_launch(void* const* d_in, const int* in_sizes, int n_in,
                              void* d_out, int out_size, void* d_ws, size_t ws_size,
                              hipStream_t stream) {
    const float* inp   = (const float*)d_in[0];
    const float* Wqkv  = (const float*)d_in[1];
    const float* bqkv  = (const float*)d_in[2];
    const float* Wo    = (const float*)d_in[3];
    const float* gamma = (const float*)d_in[4];
    const float* beta  = (const float*)d_in[5];
    float* out = (float*)d_out;

    // workspace layout (64 MB):
    //  0- 8 : inp_bf   (dead after gemm_qkv)
    //  8-14 : wqkv_bf  (dead after gemm_qkv)
    // 14-16 : wo_bf    (live until gemm_o)
    // 16-32 : qk_buf   (dead after attn)
    // 32-40 : vT_buf   (dead after attn)      -> ao_bf overlay (8 MB, gemm_o out)
    // 48-56 : ofin     (8 MB, final normalized attn_vec, read by gemm_o)
    char* ws = (char*)d_ws;
    bf16_t* inp_bf  = (bf16_t*)(ws);
    bf16_t* wqkv_bf = (bf16_t*)(ws + (8u << 20));
    bf16_t* wo_bf   = (bf16_t*)(ws + (14u << 20));
    bf16_t* qk_buf  = (bf16_t*)(ws + (16u << 20));
    bf16_t* vT_buf  = (bf16_t*)(ws + (32u << 20));
    bf16_t* ao_bf   = (bf16_t*)(ws + (32u << 20));
    bf16_t* ofin    = (bf16_t*)(ws + (48u << 20));

    cvt_all<<<8192, 256, 0, stream>>>(inp, Wqkv, Wo, inp_bf, wqkv_bf, wo_bf);
    gemm_qkv<<<dim3(24, 32), 256, 0, stream>>>(inp_bf, wqkv_bf, bqkv, qk_buf, vT_buf);
    attn_kernel<<<512, 512, 0, stream>>>(qk_buf, vT_buf, ofin);
    gemm_o<<<dim3(8, 64), 256, 0, stream>>>(ofin, wo_bf, ao_bf);
    ln_kernel<<<4096, 256, 0, stream>>>(inp, ao_bf, gamma, beta, out);
}